// Round 3
// baseline (1076.763 us; speedup 1.0000x reference)
//
#include <hip/hip_runtime.h>
#include <math.h>

// Problem constants
#define D    256      // feature dim (= C)
#define K    1024     // codebook size
#define HWX  1024     // H*W
#define NPTS 32768    // B*H*W

// Tiling: block = 256 threads, 32 points x 512 codes per k-tile
// thread microtile = 8 points x 8 codes (64 fp32 accumulators)
#define PT   32       // points per block
#define KT   512      // codes per k-tile (2 tiles cover K)
#define DCH  8        // d per stage
#define XSTR 2052     // x-tile row stride per point-group (256*8 + 4 floats)
#define ESTR 576      // e-tile row stride: 512 cols + 4-float pad per 32 cols

#define Q_OFF    1
#define PERP_OFF (1 + 8388608)
#define ENC_OFF  (2 + 8388608)

// ws layout: enorm float[1024] @0 ; counts int[1024] @4096B ; loss_accum float @8192B

__global__ __launch_bounds__(256) void vq_prep(const float* __restrict__ emb,
                                               float* __restrict__ enorm,
                                               int* __restrict__ counts,
                                               float* __restrict__ loss_accum) {
  const int t = threadIdx.x;
  const int gid = blockIdx.x * 256 + t;
  const int w = gid >> 6;          // code id, 0..1023 (grid = 256 blocks)
  const int lane = t & 63;
  float4 v = *reinterpret_cast<const float4*>(emb + (size_t)w * D + lane * 4);
  float s = v.x * v.x + v.y * v.y + v.z * v.z + v.w * v.w;
#pragma unroll
  for (int off = 32; off > 0; off >>= 1) s += __shfl_down(s, off);
  if (lane == 0) enorm[w] = s;
  if (gid < K) counts[gid] = 0;
  if (gid == 0) *loss_accum = 0.0f;
}

// No lambdas, no address-taken arrays: everything in named registers.
#define LOAD_STAGE(S)                                                          \
  {                                                                            \
    const float* bp = pf_base + (size_t)((S) >> 5) * (KT * D) + ((S) & 31) * DCH; \
    pf0 = *reinterpret_cast<const float4*>(bp);                                \
    pf1 = *reinterpret_cast<const float4*>(bp + 128 * D);                      \
    pf2 = *reinterpret_cast<const float4*>(bp + 256 * D);                      \
    pf3 = *reinterpret_cast<const float4*>(bp + 384 * D);                      \
  }

#define FMAROW(P, XS)                                                          \
  acc[P][0] += (XS) * e0; acc[P][1] += (XS) * e1;                              \
  acc[P][2] += (XS) * e2; acc[P][3] += (XS) * e3;                              \
  acc[P][4] += (XS) * e4; acc[P][5] += (XS) * e5;                              \
  acc[P][6] += (XS) * e6; acc[P][7] += (XS) * e7;

#define FMA8x8(XP0, XP1, EV0, EV1)                                             \
  {                                                                            \
    const float e0 = EV0.x, e1 = EV0.y, e2 = EV0.z, e3 = EV0.w;                \
    const float e4 = EV1.x, e5 = EV1.y, e6 = EV1.z, e7 = EV1.w;                \
    FMAROW(0, XP0.x) FMAROW(1, XP0.y) FMAROW(2, XP0.z) FMAROW(3, XP0.w)        \
    FMAROW(4, XP1.x) FMAROW(5, XP1.y) FMAROW(6, XP1.z) FMAROW(7, XP1.w)        \
  }

__global__ __launch_bounds__(256, 3) void vq_main(const float* __restrict__ x,
                                                  const float* __restrict__ emb,
                                                  const float* __restrict__ enorm,
                                                  float* __restrict__ out_q,
                                                  float* __restrict__ out_enc,
                                                  float* __restrict__ loss_accum,
                                                  int* __restrict__ counts) {
  __shared__ float xs[4 * XSTR];     // 32832 B: x tile [pg][d*8 + j], full D
  __shared__ float es[DCH * ESTR];   // 18432 B: transposed e tile [dd][col(code)]
  __shared__ int idx_s[PT];

  const int t = threadIdx.x;
  const int p0 = blockIdx.x * PT;   // first point of this block
  const int bb = p0 >> 10;          // batch index
  const int hw0 = p0 & 1023;        // hw offset (PT-aligned)
  const int pg = t & 3;             // point group (8 points each)
  const int kg = t >> 2;            // 0..63, 8 codes each

  // ---- stage x tile: NCHW -> LDS [pg][d*8+j] (coalesced 128B segments) ----
  {
    const int pi = t & 31, c0 = t >> 5;
    const int xj = pi & 7, xpg = pi >> 3;
    const float* xb = x + (size_t)bb * D * HWX + hw0 + pi;
#pragma unroll
    for (int c = c0; c < D; c += 8)
      xs[xpg * XSTR + c * 8 + xj] = xb[(size_t)c * HWX];
  }

  // e-stage prefetch: 2 lanes per code-row chunk; 4 chunks of 128 codes
  const int pf_code = t >> 1;        // 0..127
  const int pf_dl = (t & 1) * 4;     // 0 or 4
  const float* pf_base = emb + (size_t)pf_code * D + pf_dl;
  const int pf_col0 = pf_code + ((pf_code >> 5) << 2);  // physical col; +144 per chunk
  float4 pf0, pf1, pf2, pf3;
  LOAD_STAGE(0)

  const int col8 = kg * 8 + ((kg >> 2) << 2);  // my 8 codes' physical column

  float minval[8];
  int minidx[8];
#pragma unroll
  for (int p = 0; p < 8; ++p) { minval[p] = 3.4e38f; minidx[p] = 0; }

  for (int kt = 0; kt < K / KT; ++kt) {
    float acc[8][8];
#pragma unroll
    for (int p = 0; p < 8; ++p)
#pragma unroll
      for (int q = 0; q < 8; ++q) acc[p][q] = 0.0f;

    for (int dcb = 0; dcb < 32; ++dcb) {
      const int s = kt * 32 + dcb;
      const int dc = dcb * DCH;
      __syncthreads();  // prior readers done with es
      {  // write prefetched e chunk, transposed + swizzle-padded
        float* r0 = es + (pf_dl + 0) * ESTR;
        float* r1 = es + (pf_dl + 1) * ESTR;
        float* r2 = es + (pf_dl + 2) * ESTR;
        float* r3 = es + (pf_dl + 3) * ESTR;
        r0[pf_col0 +   0] = pf0.x; r1[pf_col0 +   0] = pf0.y;
        r2[pf_col0 +   0] = pf0.z; r3[pf_col0 +   0] = pf0.w;
        r0[pf_col0 + 144] = pf1.x; r1[pf_col0 + 144] = pf1.y;
        r2[pf_col0 + 144] = pf1.z; r3[pf_col0 + 144] = pf1.w;
        r0[pf_col0 + 288] = pf2.x; r1[pf_col0 + 288] = pf2.y;
        r2[pf_col0 + 288] = pf2.z; r3[pf_col0 + 288] = pf2.w;
        r0[pf_col0 + 432] = pf3.x; r1[pf_col0 + 432] = pf3.y;
        r2[pf_col0 + 432] = pf3.z; r3[pf_col0 + 432] = pf3.w;
      }
      if (s + 1 < 64) LOAD_STAGE(s + 1)  // overlaps compute below
      __syncthreads();  // es ready
      const float* xb = xs + pg * XSTR + dc * 8;
      const float* eb = es + col8;
#pragma unroll
      for (int dd = 0; dd < DCH; ++dd) {
        const float4 xp0 = *reinterpret_cast<const float4*>(xb + dd * 8);
        const float4 xp1 = *reinterpret_cast<const float4*>(xb + dd * 8 + 4);
        const float4 ev0 = *reinterpret_cast<const float4*>(eb + dd * ESTR);
        const float4 ev1 = *reinterpret_cast<const float4*>(eb + dd * ESTR + 4);
        FMA8x8(xp0, xp1, ev0, ev1)
      }
    }
    // argmin update: dist = ||e||^2 - 2 x.e (x-norm row-constant)
    const int kbase = kt * KT + kg * 8;
    const float4 en0 = *reinterpret_cast<const float4*>(enorm + kbase);
    const float4 en1 = *reinterpret_cast<const float4*>(enorm + kbase + 4);
#pragma unroll
    for (int p = 0; p < 8; ++p) {
      float m;
      m = en0.x - 2.0f * acc[p][0]; if (m < minval[p]) { minval[p] = m; minidx[p] = kbase + 0; }
      m = en0.y - 2.0f * acc[p][1]; if (m < minval[p]) { minval[p] = m; minidx[p] = kbase + 1; }
      m = en0.z - 2.0f * acc[p][2]; if (m < minval[p]) { minval[p] = m; minidx[p] = kbase + 2; }
      m = en0.w - 2.0f * acc[p][3]; if (m < minval[p]) { minval[p] = m; minidx[p] = kbase + 3; }
      m = en1.x - 2.0f * acc[p][4]; if (m < minval[p]) { minval[p] = m; minidx[p] = kbase + 4; }
      m = en1.y - 2.0f * acc[p][5]; if (m < minval[p]) { minval[p] = m; minidx[p] = kbase + 5; }
      m = en1.z - 2.0f * acc[p][6]; if (m < minval[p]) { minval[p] = m; minidx[p] = kbase + 6; }
      m = en1.w - 2.0f * acc[p][7]; if (m < minval[p]) { minval[p] = m; minidx[p] = kbase + 7; }
    }
  }

  // ---- cross-kg reduction (red arrays alias es) ----
  __syncthreads();
  float* red_val = es;                     // [64 kg][32 pi]
  int* red_idx = (int*)(es + 64 * PT);
#pragma unroll
  for (int p = 0; p < 8; ++p) {
    red_val[kg * PT + pg * 8 + p] = minval[p];
    red_idx[kg * PT + pg * 8 + p] = minidx[p];
  }
  __syncthreads();
  float dist = 0.0f;
  if (t < PT) {
    const int pi = t;
    float bv = red_val[pi];
    int bi = red_idx[pi];
    for (int g = 1; g < 64; ++g) {
      const float v = red_val[g * PT + pi];
      const int iv = red_idx[g * PT + pi];
      if (v < bv || (v == bv && iv < bi)) { bv = v; bi = iv; }  // first-index tie-break
    }
    // x-norm from LDS
    float xn = 0.0f;
    const float* xp = xs + (pi >> 3) * XSTR + (pi & 7);
    for (int d = 0; d < D; ++d) { const float xv = xp[d * 8]; xn += xv * xv; }
    dist = bv + xn;  // = ||x||^2 + ||e||^2 - 2 x.e
    idx_s[pi] = bi;
    atomicAdd(&counts[bi], 1);
  }
  if (t < 64) {  // full wave 0: lanes 32..63 contribute 0
#pragma unroll
    for (int off = 32; off > 0; off >>= 1) dist += __shfl_down(dist, off);
    if (t == 0) atomicAdd(loss_accum, dist);
  }
  __syncthreads();

  // ---- quantized output, NCHW (coalesced stores; emb gather is L2-hot) ----
  {
    const int pi = t & 31, c0 = t >> 5;
    const int row = idx_s[pi];
    const float* er = emb + (size_t)row * D;
    float* qb = out_q + (size_t)bb * D * HWX + hw0 + pi;
#pragma unroll
    for (int c = c0; c < D; c += 8) qb[(size_t)c * HWX] = er[c];
  }
  // ---- one-hot encodings (float2: enc region is only 8B-aligned) ----
  {
    float2* eb2 = reinterpret_cast<float2*>(out_enc + (size_t)p0 * K);
#pragma unroll 4
    for (int i = t; i < PT * K / 2; i += 256) {
      const int row = i >> 9;
      const int c2 = (i & 511) * 2;
      const int target = idx_s[row];
      float2 v = make_float2(0.f, 0.f);
      if (target == c2) v.x = 1.0f;
      else if (target == c2 + 1) v.y = 1.0f;
      eb2[i] = v;
    }
  }
}

__global__ __launch_bounds__(256) void vq_final(const int* __restrict__ counts,
                                                const float* __restrict__ loss_accum,
                                                float* __restrict__ out) {
  __shared__ float sh[4];
  const int t = threadIdx.x;
  float s = 0.0f;
  for (int k = t; k < K; k += 256) {
    const float p = (float)counts[k] * (1.0f / 32768.0f);
    s += p * logf(p + 1e-10f);  // p==0 -> contributes 0
  }
#pragma unroll
  for (int off = 32; off > 0; off >>= 1) s += __shfl_down(s, off);
  if ((t & 63) == 0) sh[t >> 6] = s;
  __syncthreads();
  if (t == 0) {
    const float tot = sh[0] + sh[1] + sh[2] + sh[3];
    out[PERP_OFF] = expf(-tot);
    out[0] = 0.25f * (*loss_accum) / 8388608.0f;
  }
}

extern "C" void kernel_launch(void* const* d_in, const int* in_sizes, int n_in,
                              void* d_out, int out_size, void* d_ws, size_t ws_size,
                              hipStream_t stream) {
  const float* x = (const float*)d_in[0];     // [32,256,32,32] fp32 NCHW
  const float* emb = (const float*)d_in[1];   // [1024,256] fp32
  float* out = (float*)d_out;
  float* enorm = (float*)d_ws;
  int* counts = (int*)((char*)d_ws + 4096);
  float* loss_accum = (float*)((char*)d_ws + 8192);

  hipLaunchKernelGGL(vq_prep, dim3(256), dim3(256), 0, stream,
                     emb, enorm, counts, loss_accum);
  hipLaunchKernelGGL(vq_main, dim3(NPTS / PT), dim3(256), 0, stream,
                     x, emb, enorm, out + Q_OFF, out + ENC_OFF, loss_accum, counts);
  hipLaunchKernelGGL(vq_final, dim3(1), dim3(256), 0, stream,
                     counts, loss_accum, out);
}

// Round 4
// 476.867 us; speedup vs baseline: 2.2580x; 2.2580x over previous
//
#include <hip/hip_runtime.h>
#include <math.h>

// Problem constants
#define D    256      // feature dim (= C)
#define K    1024     // codebook size
#define HWX  1024     // H*W
#define NPTS 32768    // B*H*W

// Tiling: block = 256 threads, 32 points x 512 codes per k-tile
// thread microtile = 8 points x 8 codes (64 fp32 accumulators)
#define PT   32       // points per block
#define KT   512      // codes per k-tile (2 tiles cover K)
#define DCH  8        // d per stage
#define XSTR 2052     // x-tile row stride per point-group (256*8 + 4 floats)
#define ESTR 576      // e-tile row stride: 512 cols + 4-float pad per 32 cols

#define Q_OFF    1
#define PERP_OFF (1 + 8388608)
#define ENC_OFF  (2 + 8388608)

// ws layout: enorm float[1024] @0 ; counts int[1024] @4096B ; loss_accum float @8192B

__global__ __launch_bounds__(256) void vq_prep(const float* __restrict__ emb,
                                               float* __restrict__ enorm,
                                               int* __restrict__ counts,
                                               float* __restrict__ loss_accum) {
  const int t = threadIdx.x;
  const int gid = blockIdx.x * 256 + t;
  const int w = gid >> 6;          // code id, 0..1023 (grid = 256 blocks)
  const int lane = t & 63;
  float4 v = *reinterpret_cast<const float4*>(emb + (size_t)w * D + lane * 4);
  float s = v.x * v.x + v.y * v.y + v.z * v.z + v.w * v.w;
#pragma unroll
  for (int off = 32; off > 0; off >>= 1) s += __shfl_down(s, off);
  if (lane == 0) enorm[w] = s;
  if (gid < K) counts[gid] = 0;
  if (gid == 0) *loss_accum = 0.0f;
}

// No lambdas, no address-taken arrays: everything in named registers.
#define LOAD_STAGE(S)                                                          \
  {                                                                            \
    const float* bp = pf_base + (size_t)((S) >> 5) * (KT * D) + ((S) & 31) * DCH; \
    pf0 = *reinterpret_cast<const float4*>(bp);                                \
    pf1 = *reinterpret_cast<const float4*>(bp + 128 * D);                      \
    pf2 = *reinterpret_cast<const float4*>(bp + 256 * D);                      \
    pf3 = *reinterpret_cast<const float4*>(bp + 384 * D);                      \
  }

#define FMAROW(P, XS)                                                          \
  acc[P][0] += (XS) * e0; acc[P][1] += (XS) * e1;                              \
  acc[P][2] += (XS) * e2; acc[P][3] += (XS) * e3;                              \
  acc[P][4] += (XS) * e4; acc[P][5] += (XS) * e5;                              \
  acc[P][6] += (XS) * e6; acc[P][7] += (XS) * e7;

#define FMA8x8(XP0, XP1, EV0, EV1)                                             \
  {                                                                            \
    const float e0 = EV0.x, e1 = EV0.y, e2 = EV0.z, e3 = EV0.w;                \
    const float e4 = EV1.x, e5 = EV1.y, e6 = EV1.z, e7 = EV1.w;                \
    FMAROW(0, XP0.x) FMAROW(1, XP0.y) FMAROW(2, XP0.z) FMAROW(3, XP0.w)        \
    FMAROW(4, XP1.x) FMAROW(5, XP1.y) FMAROW(6, XP1.z) FMAROW(7, XP1.w)        \
  }

__global__ __launch_bounds__(256) void vq_main(const float* __restrict__ x,
                                               const float* __restrict__ emb,
                                               const float* __restrict__ enorm,
                                               float* __restrict__ out_q,
                                               float* __restrict__ out_enc,
                                               float* __restrict__ loss_accum,
                                               int* __restrict__ counts) {
  __shared__ float xs[4 * XSTR];     // 32832 B: x tile [pg][d*8 + j], full D
  __shared__ float es[DCH * ESTR];   // 18432 B: transposed e tile [dd][col(code)]
  __shared__ int idx_s[PT];

  const int t = threadIdx.x;
  const int p0 = blockIdx.x * PT;   // first point of this block
  const int bb = p0 >> 10;          // batch index
  const int hw0 = p0 & 1023;        // hw offset (PT-aligned)
  const int pg = t & 3;             // point group (8 points each)
  const int kg = t >> 2;            // 0..63, 8 codes each

  // ---- stage x tile: NCHW -> LDS [pg][d*8+j] (coalesced 128B segments) ----
  {
    const int pi = t & 31, c0 = t >> 5;
    const int xj = pi & 7, xpg = pi >> 3;
    const float* xb = x + (size_t)bb * D * HWX + hw0 + pi;
#pragma unroll
    for (int c = c0; c < D; c += 8)
      xs[xpg * XSTR + c * 8 + xj] = xb[(size_t)c * HWX];
  }

  // e-stage prefetch: 2 lanes per code-row chunk; 4 chunks of 128 codes
  const int pf_code = t >> 1;        // 0..127
  const int pf_dl = (t & 1) * 4;     // 0 or 4
  const float* pf_base = emb + (size_t)pf_code * D + pf_dl;
  const int pf_col0 = pf_code + ((pf_code >> 5) << 2);  // physical col; +144 per chunk
  float4 pf0, pf1, pf2, pf3;
  LOAD_STAGE(0)

  const int col8 = kg * 8 + ((kg >> 2) << 2);  // my 8 codes' physical column

  float minval[8];
  int minidx[8];
#pragma unroll
  for (int p = 0; p < 8; ++p) { minval[p] = 3.4e38f; minidx[p] = 0; }

  for (int kt = 0; kt < K / KT; ++kt) {
    float acc[8][8];
#pragma unroll
    for (int p = 0; p < 8; ++p)
#pragma unroll
      for (int q = 0; q < 8; ++q) acc[p][q] = 0.0f;

    for (int dcb = 0; dcb < 32; ++dcb) {
      const int s = kt * 32 + dcb;
      const int dc = dcb * DCH;
      __syncthreads();  // prior readers done with es
      {  // write prefetched e chunk, transposed + swizzle-padded
        float* r0 = es + (pf_dl + 0) * ESTR;
        float* r1 = es + (pf_dl + 1) * ESTR;
        float* r2 = es + (pf_dl + 2) * ESTR;
        float* r3 = es + (pf_dl + 3) * ESTR;
        r0[pf_col0 +   0] = pf0.x; r1[pf_col0 +   0] = pf0.y;
        r2[pf_col0 +   0] = pf0.z; r3[pf_col0 +   0] = pf0.w;
        r0[pf_col0 + 144] = pf1.x; r1[pf_col0 + 144] = pf1.y;
        r2[pf_col0 + 144] = pf1.z; r3[pf_col0 + 144] = pf1.w;
        r0[pf_col0 + 288] = pf2.x; r1[pf_col0 + 288] = pf2.y;
        r2[pf_col0 + 288] = pf2.z; r3[pf_col0 + 288] = pf2.w;
        r0[pf_col0 + 432] = pf3.x; r1[pf_col0 + 432] = pf3.y;
        r2[pf_col0 + 432] = pf3.z; r3[pf_col0 + 432] = pf3.w;
      }
      if (s + 1 < 64) LOAD_STAGE(s + 1)  // overlaps compute below
      __syncthreads();  // es ready
      const float* xb = xs + pg * XSTR + dc * 8;
      const float* eb = es + col8;
#pragma unroll
      for (int dd = 0; dd < DCH; ++dd) {
        const float4 xp0 = *reinterpret_cast<const float4*>(xb + dd * 8);
        const float4 xp1 = *reinterpret_cast<const float4*>(xb + dd * 8 + 4);
        const float4 ev0 = *reinterpret_cast<const float4*>(eb + dd * ESTR);
        const float4 ev1 = *reinterpret_cast<const float4*>(eb + dd * ESTR + 4);
        FMA8x8(xp0, xp1, ev0, ev1)
      }
    }
    // argmin update: dist = ||e||^2 - 2 x.e (x-norm row-constant)
    const int kbase = kt * KT + kg * 8;
    const float4 en0 = *reinterpret_cast<const float4*>(enorm + kbase);
    const float4 en1 = *reinterpret_cast<const float4*>(enorm + kbase + 4);
#pragma unroll
    for (int p = 0; p < 8; ++p) {
      float m;
      m = en0.x - 2.0f * acc[p][0]; if (m < minval[p]) { minval[p] = m; minidx[p] = kbase + 0; }
      m = en0.y - 2.0f * acc[p][1]; if (m < minval[p]) { minval[p] = m; minidx[p] = kbase + 1; }
      m = en0.z - 2.0f * acc[p][2]; if (m < minval[p]) { minval[p] = m; minidx[p] = kbase + 2; }
      m = en0.w - 2.0f * acc[p][3]; if (m < minval[p]) { minval[p] = m; minidx[p] = kbase + 3; }
      m = en1.x - 2.0f * acc[p][4]; if (m < minval[p]) { minval[p] = m; minidx[p] = kbase + 4; }
      m = en1.y - 2.0f * acc[p][5]; if (m < minval[p]) { minval[p] = m; minidx[p] = kbase + 5; }
      m = en1.z - 2.0f * acc[p][6]; if (m < minval[p]) { minval[p] = m; minidx[p] = kbase + 6; }
      m = en1.w - 2.0f * acc[p][7]; if (m < minval[p]) { minval[p] = m; minidx[p] = kbase + 7; }
    }
  }

  // ---- cross-kg reduction (red arrays alias es) ----
  __syncthreads();
  float* red_val = es;                     // [64 kg][32 pi]
  int* red_idx = (int*)(es + 64 * PT);
#pragma unroll
  for (int p = 0; p < 8; ++p) {
    red_val[kg * PT + pg * 8 + p] = minval[p];
    red_idx[kg * PT + pg * 8 + p] = minidx[p];
  }
  __syncthreads();
  float dist = 0.0f;
  if (t < PT) {
    const int pi = t;
    float bv = red_val[pi];
    int bi = red_idx[pi];
    for (int g = 1; g < 64; ++g) {
      const float v = red_val[g * PT + pi];
      const int iv = red_idx[g * PT + pi];
      if (v < bv || (v == bv && iv < bi)) { bv = v; bi = iv; }  // first-index tie-break
    }
    // x-norm from LDS
    float xn = 0.0f;
    const float* xp = xs + (pi >> 3) * XSTR + (pi & 7);
    for (int d = 0; d < D; ++d) { const float xv = xp[d * 8]; xn += xv * xv; }
    dist = bv + xn;  // = ||x||^2 + ||e||^2 - 2 x.e
    idx_s[pi] = bi;
    atomicAdd(&counts[bi], 1);
  }
  if (t < 64) {  // full wave 0: lanes 32..63 contribute 0
#pragma unroll
    for (int off = 32; off > 0; off >>= 1) dist += __shfl_down(dist, off);
    if (t == 0) atomicAdd(loss_accum, dist);
  }
  __syncthreads();

  // ---- quantized output, NCHW (coalesced stores; emb gather is L2-hot) ----
  {
    const int pi = t & 31, c0 = t >> 5;
    const int row = idx_s[pi];
    const float* er = emb + (size_t)row * D;
    float* qb = out_q + (size_t)bb * D * HWX + hw0 + pi;
#pragma unroll
    for (int c = c0; c < D; c += 8) qb[(size_t)c * HWX] = er[c];
  }
  // ---- one-hot encodings (float2: enc region is only 8B-aligned) ----
  {
    float2* eb2 = reinterpret_cast<float2*>(out_enc + (size_t)p0 * K);
#pragma unroll 4
    for (int i = t; i < PT * K / 2; i += 256) {
      const int row = i >> 9;
      const int c2 = (i & 511) * 2;
      const int target = idx_s[row];
      float2 v = make_float2(0.f, 0.f);
      if (target == c2) v.x = 1.0f;
      else if (target == c2 + 1) v.y = 1.0f;
      eb2[i] = v;
    }
  }
}

__global__ __launch_bounds__(256) void vq_final(const int* __restrict__ counts,
                                                const float* __restrict__ loss_accum,
                                                float* __restrict__ out) {
  __shared__ float sh[4];
  const int t = threadIdx.x;
  float s = 0.0f;
  for (int k = t; k < K; k += 256) {
    const float p = (float)counts[k] * (1.0f / 32768.0f);
    s += p * logf(p + 1e-10f);  // p==0 -> contributes 0
  }
#pragma unroll
  for (int off = 32; off > 0; off >>= 1) s += __shfl_down(s, off);
  if ((t & 63) == 0) sh[t >> 6] = s;
  __syncthreads();
  if (t == 0) {
    const float tot = sh[0] + sh[1] + sh[2] + sh[3];
    out[PERP_OFF] = expf(-tot);
    out[0] = 0.25f * (*loss_accum) / 8388608.0f;
  }
}

extern "C" void kernel_launch(void* const* d_in, const int* in_sizes, int n_in,
                              void* d_out, int out_size, void* d_ws, size_t ws_size,
                              hipStream_t stream) {
  const float* x = (const float*)d_in[0];     // [32,256,32,32] fp32 NCHW
  const float* emb = (const float*)d_in[1];   // [1024,256] fp32
  float* out = (float*)d_out;
  float* enorm = (float*)d_ws;
  int* counts = (int*)((char*)d_ws + 4096);
  float* loss_accum = (float*)((char*)d_ws + 8192);

  hipLaunchKernelGGL(vq_prep, dim3(256), dim3(256), 0, stream,
                     emb, enorm, counts, loss_accum);
  hipLaunchKernelGGL(vq_main, dim3(NPTS / PT), dim3(256), 0, stream,
                     x, emb, enorm, out + Q_OFF, out + ENC_OFF, loss_accum, counts);
  hipLaunchKernelGGL(vq_final, dim3(1), dim3(256), 0, stream,
                     counts, loss_accum, out);
}

// Round 5
// 328.020 us; speedup vs baseline: 3.2826x; 1.4538x over previous
//
#include <hip/hip_runtime.h>
#include <math.h>

// Problem constants
#define D    256      // feature dim (= C)
#define K    1024     // codebook size
#define HWX  1024     // H*W
#define NPTS 32768    // B*H*W
#define PT   32       // points per block
#define KC   32       // codes per chunk
#define NCHUNK (K / KC)

#define Q_OFF    1
#define PERP_OFF (1 + 8388608)
#define ENC_OFF  (2 + 8388608)

typedef __attribute__((ext_vector_type(8))) short bf16x8;  // 8 bf16 in 4 VGPRs
typedef __attribute__((ext_vector_type(4))) float f32x4;

__device__ __forceinline__ unsigned short bf16_rne(float f) {
  unsigned int u = __float_as_uint(f);
  u = u + 0x7fffu + ((u >> 16) & 1u);
  return (unsigned short)(u >> 16);
}

// ws layout: enorm float[1024] @0 ; counts int[1024] @4096B ; loss_accum float @8192B

__global__ __launch_bounds__(256) void vq_prep(const float* __restrict__ emb,
                                               float* __restrict__ enorm,
                                               int* __restrict__ counts,
                                               float* __restrict__ loss_accum) {
  const int t = threadIdx.x;
  const int gid = blockIdx.x * 256 + t;
  const int w = gid >> 6;          // code id (grid = 256 blocks)
  const int lane = t & 63;
  float4 v = *reinterpret_cast<const float4*>(emb + (size_t)w * D + lane * 4);
  float s = v.x * v.x + v.y * v.y + v.z * v.z + v.w * v.w;
#pragma unroll
  for (int off = 32; off > 0; off >>= 1) s += __shfl_down(s, off);
  if (lane == 0) enorm[w] = s;
  if (gid < K) counts[gid] = 0;
  if (gid == 0) *loss_accum = 0.0f;
}

// prefetch one chunk of e (32 codes x 256 d) into 8 float4 regs, coalesced
#define PF_LOAD(CN)                                                            \
  {                                                                            \
    const float* ebase = emb + (size_t)((CN) * KC + (t >> 3)) * D + (t & 7) * 4; \
    pf0 = *(const float4*)(ebase +   0); pf1 = *(const float4*)(ebase +  32);  \
    pf2 = *(const float4*)(ebase +  64); pf3 = *(const float4*)(ebase +  96);  \
    pf4 = *(const float4*)(ebase + 128); pf5 = *(const float4*)(ebase + 160);  \
    pf6 = *(const float4*)(ebase + 192); pf7 = *(const float4*)(ebase + 224);  \
  }

// convert one float4 (kstep I) to hi/lo bf16 and store into e-frag layout
#define EST(I, PF)                                                             \
  {                                                                            \
    unsigned short h0 = bf16_rne(PF.x), h1 = bf16_rne(PF.y);                   \
    unsigned short h2 = bf16_rne(PF.z), h3 = bf16_rne(PF.w);                   \
    float f0 = __uint_as_float((unsigned)h0 << 16);                            \
    float f1 = __uint_as_float((unsigned)h1 << 16);                            \
    float f2 = __uint_as_float((unsigned)h2 << 16);                            \
    float f3 = __uint_as_float((unsigned)h3 << 16);                            \
    unsigned short l0 = bf16_rne(PF.x - f0), l1 = bf16_rne(PF.y - f1);         \
    unsigned short l2 = bf16_rne(PF.z - f2), l3 = bf16_rne(PF.w - f3);         \
    uint2 uh = make_uint2((unsigned)h0 | ((unsigned)h1 << 16),                 \
                          (unsigned)h2 | ((unsigned)h3 << 16));                \
    uint2 ul = make_uint2((unsigned)l0 | ((unsigned)l1 << 16),                 \
                          (unsigned)l2 | ((unsigned)l3 << 16));                \
    *(uint2*)&fbuf[((est_ct * 8 + (I)) * 2 + 0) * 512 + est_so] = uh;          \
    *(uint2*)&fbuf[((est_ct * 8 + (I)) * 2 + 1) * 512 + est_so] = ul;          \
  }

#define AHOIST(KS)                                                             \
  ah##KS = *(const bf16x8*)&fbuf[((rt * 8 + KS) * 2 + 0) * 512 + lane * 8];    \
  al##KS = *(const bf16x8*)&fbuf[((rt * 8 + KS) * 2 + 1) * 512 + lane * 8];

#define KSTEP(KS)                                                              \
  {                                                                            \
    bf16x8 bh = *(const bf16x8*)&fbuf[((cg * 8 + KS) * 2 + 0) * 512 + lane * 8]; \
    bf16x8 bl = *(const bf16x8*)&fbuf[((cg * 8 + KS) * 2 + 1) * 512 + lane * 8]; \
    acc = __builtin_amdgcn_mfma_f32_16x16x32_bf16(ah##KS, bh, acc, 0, 0, 0);   \
    acc = __builtin_amdgcn_mfma_f32_16x16x32_bf16(al##KS, bh, acc, 0, 0, 0);   \
    acc = __builtin_amdgcn_mfma_f32_16x16x32_bf16(ah##KS, bl, acc, 0, 0, 0);   \
    acc = __builtin_amdgcn_mfma_f32_16x16x32_bf16(al##KS, bl, acc, 0, 0, 0);   \
  }

__global__ __launch_bounds__(256) void vq_main(const float* __restrict__ x,
                                               const float* __restrict__ emb,
                                               const float* __restrict__ enorm,
                                               float* __restrict__ out_q,
                                               float* __restrict__ out_enc,
                                               float* __restrict__ loss_accum,
                                               int* __restrict__ counts) {
  // fbuf: x-fragments during prologue (transit), e-fragments in main loop.
  // frag(slot, kstep, part): 1024 B block, lane-contiguous 16 B units.
  __shared__ __align__(16) unsigned short fbuf[16384];  // 32 KB
  __shared__ float en_s[K];                             // 4 KB
  __shared__ float xn_part[256];
  __shared__ float red_val[64];
  __shared__ int red_idx[64];
  __shared__ int idx_s[PT];

  const int t = threadIdx.x;
  const int lane = t & 63;
  const int w = t >> 6;
  const int rt = w & 1;       // row tile: points rt*16..rt*16+15
  const int cg = w >> 1;      // col group: coltile within each chunk
  const int p0 = blockIdx.x * PT;
  const int bb = p0 >> 10;
  const int hw0 = p0 & 1023;

  float4 pf0, pf1, pf2, pf3, pf4, pf5, pf6, pf7;

  // ---- stage x: NCHW -> hi/lo bf16 A-fragment layout in fbuf; accumulate x^2 ----
  {
    const int pt = t & 31;
    const int rtp = pt >> 4;
    const int mrow = pt & 15;
    const float* xb = x + (size_t)bb * (D * HWX) + hw0 + pt;
    float xn_acc = 0.0f;
    for (int c = t >> 5; c < D; c += 8) {
      const float f = xb[(size_t)c * HWX];
      const unsigned short h = bf16_rne(f);
      const float fh = __uint_as_float((unsigned)h << 16);
      const unsigned short l = bf16_rne(f - fh);
      xn_acc += f * f;
      const int ks = c >> 5, kg = (c >> 3) & 3, j = c & 7;
      const int L = mrow + 16 * kg;
      fbuf[((rtp * 8 + ks) * 2 + 0) * 512 + L * 8 + j] = h;
      fbuf[((rtp * 8 + ks) * 2 + 1) * 512 + L * 8 + j] = l;
    }
    xn_part[t] = xn_acc;
  }
  for (int i = t; i < K; i += 256) en_s[i] = enorm[i];
  PF_LOAD(0)
  __syncthreads();

  // ---- hoist A-fragments (this wave's row tile) into registers ----
  bf16x8 ah0, ah1, ah2, ah3, ah4, ah5, ah6, ah7;
  bf16x8 al0, al1, al2, al3, al4, al5, al6, al7;
  AHOIST(0) AHOIST(1) AHOIST(2) AHOIST(3)
  AHOIST(4) AHOIST(5) AHOIST(6) AHOIST(7)

  // e-stage write coords for this thread
  const int est_c = t >> 3, est_qb = t & 7;
  const int est_ct = est_c >> 4;
  const int est_so = ((est_c & 15) + 16 * (est_qb >> 1)) * 8 + (est_qb & 1) * 4;

  float mv0 = 3.4e38f, mv1 = 3.4e38f, mv2 = 3.4e38f, mv3 = 3.4e38f;
  int mi0 = 0, mi1 = 0, mi2 = 0, mi3 = 0;

  for (int cn = 0; cn < NCHUNK; ++cn) {
    __syncthreads();  // prior readers done with fbuf (also drains A-hoist on cn=0)
    EST(0, pf0) EST(1, pf1) EST(2, pf2) EST(3, pf3)
    EST(4, pf4) EST(5, pf5) EST(6, pf6) EST(7, pf7)
    if (cn + 1 < NCHUNK) PF_LOAD(cn + 1)  // overlaps compute below
    __syncthreads();  // e-frags ready

    f32x4 acc = {0.f, 0.f, 0.f, 0.f};
    KSTEP(0) KSTEP(1) KSTEP(2) KSTEP(3)
    KSTEP(4) KSTEP(5) KSTEP(6) KSTEP(7)

    const int code = cn * KC + cg * 16 + (lane & 15);
    const float en_l = en_s[code];
    float m;
    m = en_l - 2.0f * acc[0]; if (m < mv0) { mv0 = m; mi0 = code; }
    m = en_l - 2.0f * acc[1]; if (m < mv1) { mv1 = m; mi1 = code; }
    m = en_l - 2.0f * acc[2]; if (m < mv2) { mv2 = m; mi2 = code; }
    m = en_l - 2.0f * acc[3]; if (m < mv3) { mv3 = m; mi3 = code; }
  }

  // ---- argmin reduce: butterfly over the 16 lane-columns (first-index ties) ----
  for (int off = 1; off < 16; off <<= 1) {
    float ov; int oi;
    ov = __shfl_xor(mv0, off); oi = __shfl_xor(mi0, off);
    if (ov < mv0 || (ov == mv0 && oi < mi0)) { mv0 = ov; mi0 = oi; }
    ov = __shfl_xor(mv1, off); oi = __shfl_xor(mi1, off);
    if (ov < mv1 || (ov == mv1 && oi < mi1)) { mv1 = ov; mi1 = oi; }
    ov = __shfl_xor(mv2, off); oi = __shfl_xor(mi2, off);
    if (ov < mv2 || (ov == mv2 && oi < mi2)) { mv2 = ov; mi2 = oi; }
    ov = __shfl_xor(mv3, off); oi = __shfl_xor(mi3, off);
    if (ov < mv3 || (ov == mv3 && oi < mi3)) { mv3 = ov; mi3 = oi; }
  }
  if ((lane & 15) == 0) {
    const int pb = rt * 16 + (lane >> 4) * 4;  // D-layout: row = quad*4 + reg
    red_val[cg * 32 + pb + 0] = mv0; red_idx[cg * 32 + pb + 0] = mi0;
    red_val[cg * 32 + pb + 1] = mv1; red_idx[cg * 32 + pb + 1] = mi1;
    red_val[cg * 32 + pb + 2] = mv2; red_idx[cg * 32 + pb + 2] = mi2;
    red_val[cg * 32 + pb + 3] = mv3; red_idx[cg * 32 + pb + 3] = mi3;
  }
  __syncthreads();
  float dist = 0.0f;
  if (t < PT) {
    float bv = red_val[t]; int bi = red_idx[t];
    const float v1 = red_val[32 + t]; const int i1 = red_idx[32 + t];
    if (v1 < bv || (v1 == bv && i1 < bi)) { bv = v1; bi = i1; }
    float xn = 0.0f;
#pragma unroll
    for (int g = 0; g < 8; ++g) xn += xn_part[t + 32 * g];
    dist = bv + xn;  // = ||x||^2 + ||e||^2 - 2 x.e
    idx_s[t] = bi;
    atomicAdd(&counts[bi], 1);
  }
  if (t < 64) {  // wave 0: lanes 32..63 contribute 0
#pragma unroll
    for (int off = 32; off > 0; off >>= 1) dist += __shfl_down(dist, off);
    if (t == 0) atomicAdd(loss_accum, dist);
  }
  __syncthreads();

  // ---- quantized output, NCHW (coalesced stores; emb gather is L2-hot) ----
  {
    const int pi = t & 31, c0 = t >> 5;
    const int row = idx_s[pi];
    const float* er = emb + (size_t)row * D;
    float* qb = out_q + (size_t)bb * D * HWX + hw0 + pi;
#pragma unroll
    for (int c = c0; c < D; c += 8) qb[(size_t)c * HWX] = er[c];
  }
  // ---- one-hot encodings (float2: enc region is only 8B-aligned) ----
  {
    float2* eb2 = reinterpret_cast<float2*>(out_enc + (size_t)p0 * K);
#pragma unroll 4
    for (int i = t; i < PT * K / 2; i += 256) {
      const int row = i >> 9;
      const int c2 = (i & 511) * 2;
      const int target = idx_s[row];
      float2 v = make_float2(0.f, 0.f);
      if (target == c2) v.x = 1.0f;
      else if (target == c2 + 1) v.y = 1.0f;
      eb2[i] = v;
    }
  }
}

__global__ __launch_bounds__(256) void vq_final(const int* __restrict__ counts,
                                                const float* __restrict__ loss_accum,
                                                float* __restrict__ out) {
  __shared__ float sh[4];
  const int t = threadIdx.x;
  float s = 0.0f;
  for (int k = t; k < K; k += 256) {
    const float p = (float)counts[k] * (1.0f / 32768.0f);
    s += p * logf(p + 1e-10f);  // p==0 -> contributes 0
  }
#pragma unroll
  for (int off = 32; off > 0; off >>= 1) s += __shfl_down(s, off);
  if ((t & 63) == 0) sh[t >> 6] = s;
  __syncthreads();
  if (t == 0) {
    const float tot = sh[0] + sh[1] + sh[2] + sh[3];
    out[PERP_OFF] = expf(-tot);
    out[0] = 0.25f * (*loss_accum) / 8388608.0f;
  }
}

extern "C" void kernel_launch(void* const* d_in, const int* in_sizes, int n_in,
                              void* d_out, int out_size, void* d_ws, size_t ws_size,
                              hipStream_t stream) {
  const float* x = (const float*)d_in[0];     // [32,256,32,32] fp32 NCHW
  const float* emb = (const float*)d_in[1];   // [1024,256] fp32
  float* out = (float*)d_out;
  float* enorm = (float*)d_ws;
  int* counts = (int*)((char*)d_ws + 4096);
  float* loss_accum = (float*)((char*)d_ws + 8192);

  hipLaunchKernelGGL(vq_prep, dim3(256), dim3(256), 0, stream,
                     emb, enorm, counts, loss_accum);
  hipLaunchKernelGGL(vq_main, dim3(NPTS / PT), dim3(256), 0, stream,
                     x, emb, enorm, out + Q_OFF, out + ENC_OFF, loss_accum, counts);
  hipLaunchKernelGGL(vq_final, dim3(1), dim3(256), 0, stream,
                     counts, loss_accum, out);
}

// Round 6
// 287.745 us; speedup vs baseline: 3.7421x; 1.1400x over previous
//
#include <hip/hip_runtime.h>
#include <math.h>

// Problem constants
#define D    256      // feature dim (= C)
#define K    1024     // codebook size
#define HWX  1024     // H*W
#define NPTS 32768    // B*H*W
#define PT   64       // points per block
#define NPAIR 32      // pairs of 16-code chunks (64 chunks of 16 codes)

#define Q_OFF    1
#define PERP_OFF (1 + 8388608)
#define ENC_OFF  (2 + 8388608)

// ws layout: enorm float[1024] @0 ; counts int[1024] @4096 ; loss @8192 ;
//            e-fragments (hi/lo bf16, MFMA B layout) @16384, 1 MB
#define WS_FRAG_OFF 16384

typedef __attribute__((ext_vector_type(8))) short bf16x8;  // 8 bf16 = 4 VGPRs
typedef __attribute__((ext_vector_type(4))) float f32x4;

__device__ __forceinline__ unsigned short bf16_rne(float f) {
  unsigned int u = __float_as_uint(f);
  u = u + 0x7fffu + ((u >> 16) & 1u);
  return (unsigned short)(u >> 16);
}

#define CONV(F, H, L)                                                          \
  {                                                                            \
    H = bf16_rne(F);                                                           \
    const float fh_ = __uint_as_float((unsigned)(H) << 16);                    \
    L = bf16_rne((F)-fh_);                                                     \
  }

// Build e-fragments: frag[cn(64)][ks(8)][part(2)] = 1024 B, lane-contiguous
// 16 B units. B-operand layout (m89): lane = (code&15) + 16*quad holds 8 bf16
// of k = ks*32 + quad*8 + j. Also computes enorm, zeros counts/loss.
__global__ __launch_bounds__(256) void vq_frag(const float* __restrict__ emb,
                                               unsigned int* __restrict__ frag,
                                               float* __restrict__ enorm,
                                               int* __restrict__ counts,
                                               float* __restrict__ loss_accum) {
  const int gid = blockIdx.x * 256 + threadIdx.x;  // 128 blocks -> 32768
  const int c = gid >> 5, g = gid & 31;            // code, k-group of 8
  const float* src = emb + (size_t)c * D + g * 8;
  const float4 a = *(const float4*)src;
  const float4 b = *(const float4*)(src + 4);
  float s = a.x * a.x + a.y * a.y + a.z * a.z + a.w * a.w +
            b.x * b.x + b.y * b.y + b.z * b.z + b.w * b.w;
#pragma unroll
  for (int off = 1; off < 32; off <<= 1) s += __shfl_xor(s, off);
  if (g == 0) enorm[c] = s;
  unsigned short h0, h1, h2, h3, h4, h5, h6, h7;
  unsigned short l0, l1, l2, l3, l4, l5, l6, l7;
  CONV(a.x, h0, l0) CONV(a.y, h1, l1) CONV(a.z, h2, l2) CONV(a.w, h3, l3)
  CONV(b.x, h4, l4) CONV(b.y, h5, l5) CONV(b.z, h6, l6) CONV(b.w, h7, l7)
  uint4 uh, ul;
  uh.x = (unsigned)h0 | ((unsigned)h1 << 16); uh.y = (unsigned)h2 | ((unsigned)h3 << 16);
  uh.z = (unsigned)h4 | ((unsigned)h5 << 16); uh.w = (unsigned)h6 | ((unsigned)h7 << 16);
  ul.x = (unsigned)l0 | ((unsigned)l1 << 16); ul.y = (unsigned)l2 | ((unsigned)l3 << 16);
  ul.z = (unsigned)l4 | ((unsigned)l5 << 16); ul.w = (unsigned)l6 | ((unsigned)l7 << 16);
  const int fragidx = (c >> 4) * 16 + (g >> 2) * 2;          // cn*16 + ks*2 (+part)
  const int Lo = ((c & 15) + 16 * (g & 3)) * 4;              // lane*16 B in uints
  *(uint4*)(frag + (size_t)fragidx * 256 + Lo) = uh;
  *(uint4*)(frag + (size_t)(fragidx + 1) * 256 + Lo) = ul;
  if (gid < K) counts[gid] = 0;
  if (gid == 0) *loss_accum = 0.0f;
}

// async copy of one 1024 B fragment per instruction (lane-contiguous 16 B)
#define ISSUE_PAIR(P, SEL)                                                     \
  {                                                                            \
    const unsigned* gsrc = fragg + (((size_t)(P)*32 + w * 8) * 256) + lane * 4; \
    unsigned short* ldst = fbuf + (SEL)*16384 + (w * 8) * 512;                 \
    _Pragma("unroll") for (int q = 0; q < 8; ++q)                              \
        __builtin_amdgcn_global_load_lds(                                      \
            (const __attribute__((address_space(1))) unsigned*)(gsrc + q * 256), \
            (__attribute__((address_space(3))) unsigned*)(ldst + q * 512),     \
            16, 0, 0);                                                         \
  }

#define AH(RTL, KS)                                                            \
  ah##RTL##_##KS = *(const bf16x8*)&fbuf[(((pg * 2 + RTL) * 8 + KS) * 2 + 0) * 512 + lane * 8]; \
  al##RTL##_##KS = *(const bf16x8*)&fbuf[(((pg * 2 + RTL) * 8 + KS) * 2 + 1) * 512 + lane * 8];

#define KS(KSv)                                                                \
  {                                                                            \
    const bf16x8 bh = *(const bf16x8*)&fbuf[bufo + (KSv * 2 + 0) * 512 + lane * 8]; \
    const bf16x8 bl = *(const bf16x8*)&fbuf[bufo + (KSv * 2 + 1) * 512 + lane * 8]; \
    acc0 = __builtin_amdgcn_mfma_f32_16x16x32_bf16(ah0_##KSv, bh, acc0, 0, 0, 0); \
    acc0 = __builtin_amdgcn_mfma_f32_16x16x32_bf16(al0_##KSv, bh, acc0, 0, 0, 0); \
    acc0 = __builtin_amdgcn_mfma_f32_16x16x32_bf16(ah0_##KSv, bl, acc0, 0, 0, 0); \
    acc0 = __builtin_amdgcn_mfma_f32_16x16x32_bf16(al0_##KSv, bl, acc0, 0, 0, 0); \
    acc1 = __builtin_amdgcn_mfma_f32_16x16x32_bf16(ah1_##KSv, bh, acc1, 0, 0, 0); \
    acc1 = __builtin_amdgcn_mfma_f32_16x16x32_bf16(al1_##KSv, bh, acc1, 0, 0, 0); \
    acc1 = __builtin_amdgcn_mfma_f32_16x16x32_bf16(ah1_##KSv, bl, acc1, 0, 0, 0); \
    acc1 = __builtin_amdgcn_mfma_f32_16x16x32_bf16(al1_##KSv, bl, acc1, 0, 0, 0); \
  }

__global__ __launch_bounds__(256) void vq_main(const float* __restrict__ x,
                                               const unsigned int* __restrict__ fragg,
                                               const float* __restrict__ emb,
                                               const float* __restrict__ enorm,
                                               float* __restrict__ out_q,
                                               float* __restrict__ out_enc,
                                               float* __restrict__ loss_accum,
                                               int* __restrict__ counts) {
  // fbuf: A-fragment transit in prologue; then 2 x 32 KB e pair-buffers.
  __shared__ __align__(16) unsigned short fbuf[32768];  // 64 KB
  __shared__ float en_s[K];                             // 4 KB
  __shared__ float xn_part[256];
  __shared__ float red_val[128];
  __shared__ int red_idx[128];
  __shared__ int idx_s[PT];

  const int t = threadIdx.x;
  const int lane = t & 63;
  const int w = t >> 6;
  const int pg = w >> 1;     // point group: pts pg*32 .. pg*32+31
  const int par = w & 1;     // chunk parity
  const int p0 = blockIdx.x * PT;
  const int bb = p0 >> 10;
  const int hw0 = p0 & 1023;

  // ---- stage x: NCHW -> hi/lo bf16 A-fragments in fbuf; x^2 partials ----
  {
    const int pt = t & 63, c0 = t >> 6;
    const int rt = pt >> 4, mrow = pt & 15;
    const float* xb = x + (size_t)bb * (D * HWX) + hw0 + pt;
    float xn = 0.0f;
    for (int c = c0; c < D; c += 4) {
      const float f = xb[(size_t)c * HWX];
      unsigned short h, l;
      CONV(f, h, l)
      xn += f * f;
      const int ks = c >> 5, quad = (c >> 3) & 3, j = c & 7;
      const int Lr = mrow + 16 * quad;
      fbuf[((rt * 8 + ks) * 2 + 0) * 512 + Lr * 8 + j] = h;
      fbuf[((rt * 8 + ks) * 2 + 1) * 512 + Lr * 8 + j] = l;
    }
    xn_part[t] = xn;
  }
  for (int i = t; i < K; i += 256) en_s[i] = enorm[i];
  __syncthreads();

  // ---- hoist this wave's 32 points of A into registers (128 VGPRs) ----
  bf16x8 ah0_0, ah0_1, ah0_2, ah0_3, ah0_4, ah0_5, ah0_6, ah0_7;
  bf16x8 al0_0, al0_1, al0_2, al0_3, al0_4, al0_5, al0_6, al0_7;
  bf16x8 ah1_0, ah1_1, ah1_2, ah1_3, ah1_4, ah1_5, ah1_6, ah1_7;
  bf16x8 al1_0, al1_1, al1_2, al1_3, al1_4, al1_5, al1_6, al1_7;
  AH(0, 0) AH(0, 1) AH(0, 2) AH(0, 3) AH(0, 4) AH(0, 5) AH(0, 6) AH(0, 7)
  AH(1, 0) AH(1, 1) AH(1, 2) AH(1, 3) AH(1, 4) AH(1, 5) AH(1, 6) AH(1, 7)
  __syncthreads();  // all hoists done; fbuf free for e staging

  float mv[8];
  int mi[8];
#pragma unroll
  for (int i = 0; i < 8; ++i) { mv[i] = 3.4e38f; mi[i] = 0; }

  ISSUE_PAIR(0, 0)
  int sel = 0;
  for (int p = 0; p < NPAIR; ++p) {
    __syncthreads();  // barrier drains vmcnt -> current pair resident; other buf free
    if (p + 1 < NPAIR) ISSUE_PAIR(p + 1, sel ^ 1)  // overlaps compute below
    const int bufo = sel * 16384 + par * 16 * 512;
    f32x4 acc0 = {0.f, 0.f, 0.f, 0.f};
    f32x4 acc1 = {0.f, 0.f, 0.f, 0.f};
    KS(0) KS(1) KS(2) KS(3) KS(4) KS(5) KS(6) KS(7)
    const int code = (p * 2 + par) * 16 + (lane & 15);
    const float en_l = en_s[code];
    float m;
    m = en_l - 2.0f * acc0[0]; if (m < mv[0]) { mv[0] = m; mi[0] = code; }
    m = en_l - 2.0f * acc0[1]; if (m < mv[1]) { mv[1] = m; mi[1] = code; }
    m = en_l - 2.0f * acc0[2]; if (m < mv[2]) { mv[2] = m; mi[2] = code; }
    m = en_l - 2.0f * acc0[3]; if (m < mv[3]) { mv[3] = m; mi[3] = code; }
    m = en_l - 2.0f * acc1[0]; if (m < mv[4]) { mv[4] = m; mi[4] = code; }
    m = en_l - 2.0f * acc1[1]; if (m < mv[5]) { mv[5] = m; mi[5] = code; }
    m = en_l - 2.0f * acc1[2]; if (m < mv[6]) { mv[6] = m; mi[6] = code; }
    m = en_l - 2.0f * acc1[3]; if (m < mv[7]) { mv[7] = m; mi[7] = code; }
    sel ^= 1;
  }

  // ---- argmin butterfly over the 16 lane-columns (first-index ties) ----
#pragma unroll
  for (int off = 1; off < 16; off <<= 1) {
#pragma unroll
    for (int i = 0; i < 8; ++i) {
      const float ov = __shfl_xor(mv[i], off);
      const int oi = __shfl_xor(mi[i], off);
      if (ov < mv[i] || (ov == mv[i] && oi < mi[i])) { mv[i] = ov; mi[i] = oi; }
    }
  }
  if ((lane & 15) == 0) {
    const int quad = lane >> 4;  // D-layout row = quad*4 + reg
#pragma unroll
    for (int i = 0; i < 8; ++i) {
      const int loc = (i >> 2) * 16 + quad * 4 + (i & 3);
      red_val[w * 32 + loc] = mv[i];
      red_idx[w * 32 + loc] = mi[i];
    }
  }
  __syncthreads();
  float dist = 0.0f;
  if (t < PT) {  // merge chunk parities
    const int pgm = t >> 5, loc = t & 31;
    float bv = red_val[(pgm * 2) * 32 + loc];
    int bi = red_idx[(pgm * 2) * 32 + loc];
    const float v1 = red_val[(pgm * 2 + 1) * 32 + loc];
    const int i1 = red_idx[(pgm * 2 + 1) * 32 + loc];
    if (v1 < bv || (v1 == bv && i1 < bi)) { bv = v1; bi = i1; }
    float xn = 0.0f;
#pragma unroll
    for (int g = 0; g < 4; ++g) xn += xn_part[t + 64 * g];
    dist = bv + xn;  // = ||x||^2 + ||e||^2 - 2 x.e
    idx_s[t] = bi;
    atomicAdd(&counts[bi], 1);
  }
  if (t < 64) {
#pragma unroll
    for (int off = 32; off > 0; off >>= 1) dist += __shfl_down(dist, off);
    if (t == 0) atomicAdd(loss_accum, dist);
  }
  __syncthreads();

  // ---- quantized output, NCHW (coalesced; emb row gather is L2-hot) ----
  {
    const int pt = t & 63, c0 = t >> 6;
    const int row = idx_s[pt];
    const float* er = emb + (size_t)row * D;
    float* qb = out_q + (size_t)bb * D * HWX + hw0 + pt;
#pragma unroll
    for (int c = c0; c < D; c += 4) qb[(size_t)c * HWX] = er[c];
  }
  // ---- one-hot encodings (float2: enc region is only 8B-aligned) ----
  {
    float2* eb2 = reinterpret_cast<float2*>(out_enc + (size_t)p0 * K);
#pragma unroll 4
    for (int i = t; i < PT * K / 2; i += 256) {
      const int row = i >> 9;
      const int c2 = (i & 511) * 2;
      const int target = idx_s[row];
      float2 v = make_float2(0.f, 0.f);
      if (target == c2) v.x = 1.0f;
      else if (target == c2 + 1) v.y = 1.0f;
      eb2[i] = v;
    }
  }
}

__global__ __launch_bounds__(256) void vq_final(const int* __restrict__ counts,
                                                const float* __restrict__ loss_accum,
                                                float* __restrict__ out) {
  __shared__ float sh[4];
  const int t = threadIdx.x;
  float s = 0.0f;
  for (int k = t; k < K; k += 256) {
    const float p = (float)counts[k] * (1.0f / 32768.0f);
    s += p * logf(p + 1e-10f);  // p==0 -> contributes 0
  }
#pragma unroll
  for (int off = 32; off > 0; off >>= 1) s += __shfl_down(s, off);
  if ((t & 63) == 0) sh[t >> 6] = s;
  __syncthreads();
  if (t == 0) {
    const float tot = sh[0] + sh[1] + sh[2] + sh[3];
    out[PERP_OFF] = expf(-tot);
    out[0] = 0.25f * (*loss_accum) / 8388608.0f;
  }
}

extern "C" void kernel_launch(void* const* d_in, const int* in_sizes, int n_in,
                              void* d_out, int out_size, void* d_ws, size_t ws_size,
                              hipStream_t stream) {
  const float* x = (const float*)d_in[0];     // [32,256,32,32] fp32 NCHW
  const float* emb = (const float*)d_in[1];   // [1024,256] fp32
  float* out = (float*)d_out;
  float* enorm = (float*)d_ws;
  int* counts = (int*)((char*)d_ws + 4096);
  float* loss_accum = (float*)((char*)d_ws + 8192);
  unsigned int* fragg = (unsigned int*)((char*)d_ws + WS_FRAG_OFF);  // 1 MB

  hipLaunchKernelGGL(vq_frag, dim3(128), dim3(256), 0, stream,
                     emb, fragg, enorm, counts, loss_accum);
  hipLaunchKernelGGL(vq_main, dim3(NPTS / PT), dim3(256), 0, stream,
                     x, fragg, emb, enorm, out + Q_OFF, out + ENC_OFF,
                     loss_accum, counts);
  hipLaunchKernelGGL(vq_final, dim3(1), dim3(256), 0, stream,
                     counts, loss_accum, out);
}